// Round 5
// baseline (234.508 us; speedup 1.0000x reference)
//
#include <hip/hip_runtime.h>

// LIF forward recurrence:
//   mem0 = x[0]; spike0 = (mem0 > 0.5)
//   mem_t = mem_{t-1} * 0.25 * (1 - spike_{t-1}) + x_t ; spike_t = (mem_t > 0.5)
// Output: spikes [T, B, D] float32.
//
// History:
//   R2: float4 chunked, compiler pipeline, NT stores -> 81 us, 2.48 TB/s.
//   R3: float2 + empty asm fences -> scratch spills, confounded. 110 us.
//   R4: asm-forced DEPTH=16 -> spilled in-flight asm load dests. FAILED.
//   R5: asm-forced DEPTH=8 + NT store epilogue -> 98 us, 2.0 TB/s.
//       Per-wave MLP falsified (or masked by the NT store phase).
//   R6: float2, 32 waves/CU, NT interleaved -> ~100+ us, 1.9 TB/s.
//       TLP falsified.
//   => Every variant plateaus at 2.0-2.5 TB/s. Common factor: nontemporal
//      stores. NT bypasses L2/L3 absorption (WRITE_SIZE pinned at 131 MB =
//      full output to HBM synchronously) and store-completion shares vmcnt
//      with loads, stalling each wave on HBM write-queue acceptance every
//      timestep.
//
// R7: single-variable A/B vs R2 — same structure, PLAIN CACHED STORES.
// Writes ack fast in L2 and drain to HBM behind the read front.

constexpr int   T_STEPS = 32;
constexpr int   CHUNK   = 8;
constexpr float THRESH  = 0.5f;
constexpr float DECAY   = 0.25f;

typedef float v4f __attribute__((ext_vector_type(4)));

__device__ __forceinline__ void load_chunk(float4* buf, const float4* __restrict__ xp,
                                           int t0, int n4) {
#pragma unroll
    for (int k = 0; k < CHUNK; ++k)
        buf[k] = xp[(size_t)(t0 + k) * (size_t)n4];
}

template <int T0>
__device__ __forceinline__ void compute_chunk(const float4* buf, float4& mem, float4& s,
                                              float4* __restrict__ op, int n4) {
#pragma unroll
    for (int k = 0; k < CHUNK; ++k) {
        float4 v = buf[k];
        if (T0 + k == 0) {
            mem = v;  // mem0 = x[0]
        } else {
            mem.x = mem.x * (DECAY * (1.0f - s.x)) + v.x;
            mem.y = mem.y * (DECAY * (1.0f - s.y)) + v.y;
            mem.z = mem.z * (DECAY * (1.0f - s.z)) + v.z;
            mem.w = mem.w * (DECAY * (1.0f - s.w)) + v.w;
        }
        s.x = mem.x > THRESH ? 1.0f : 0.0f;
        s.y = mem.y > THRESH ? 1.0f : 0.0f;
        s.z = mem.z > THRESH ? 1.0f : 0.0f;
        s.w = mem.w > THRESH ? 1.0f : 0.0f;
        v4f sv = {s.x, s.y, s.z, s.w};
        *(v4f*)(op + (size_t)(T0 + k) * (size_t)n4) = sv;  // cached store
    }
}

__global__ __launch_bounds__(256) void lif_fwd_kernel(
    const float4* __restrict__ x,   // [T, n4]
    float4* __restrict__ out,       // [T, n4]
    int n4)
{
    int i = blockIdx.x * 256 + threadIdx.x;
    if (i >= n4) return;

    const float4* xp = x + i;
    float4*       op = out + i;

    float4 bufA[CHUNK], bufB[CHUNK];
    float4 mem, s;

    // Pipeline: A(0-7), B(8-15) in flight; compute A; load A(16-23);
    // compute B; load B(24-31); compute A; compute B.
    load_chunk(bufA, xp, 0, n4);
    load_chunk(bufB, xp, 8, n4);
    compute_chunk<0>(bufA, mem, s, op, n4);
    load_chunk(bufA, xp, 16, n4);
    compute_chunk<8>(bufB, mem, s, op, n4);
    load_chunk(bufB, xp, 24, n4);
    compute_chunk<16>(bufA, mem, s, op, n4);
    compute_chunk<24>(bufB, mem, s, op, n4);
}

extern "C" void kernel_launch(void* const* d_in, const int* in_sizes, int n_in,
                              void* d_out, int out_size, void* d_ws, size_t ws_size,
                              hipStream_t stream) {
    const float* x = (const float*)d_in[0];
    float* out = (float*)d_out;

    const int total = in_sizes[0];        // T * B * D = 33_554_432
    const int n     = total / T_STEPS;    // B * D     = 1_048_576
    const int n4    = n / 4;              // 262_144 float4 work items

    const int block = 256;
    const int grid  = (n4 + block - 1) / block;  // 1024 blocks

    lif_fwd_kernel<<<grid, block, 0, stream>>>(
        reinterpret_cast<const float4*>(x),
        reinterpret_cast<float4*>(out),
        n4);
}